// Round 7
// baseline (607.023 us; speedup 1.0000x reference)
//
#include <hip/hip_runtime.h>
#include <cstdint>

#define FEAT 4096
#define DIN  64
#define HS   32
#define NL   8
#define TT   300
#define BB   64
#define G4   128           // 4*HS
#define MROWS (BB*TT)      // 19200
#define KS    4            // K-split for big GEMM
#define KSLICE (FEAT/KS)   // 1024
#define BK    64
#define NCHUNK (KSLICE/BK) // 16
#define NW    4            // waves in lstm block (2 layers each)
#define NSUP  (TT + NW - 1) // 303 supersteps

typedef __bf16 bf16x8 __attribute__((ext_vector_type(8)));
typedef float  f32x4  __attribute__((ext_vector_type(4)));
typedef unsigned short u16x8 __attribute__((ext_vector_type(8)));

__device__ __forceinline__ float sigm(float x){ return __fdividef(1.f, 1.f + __expf(-x)); }
__device__ __forceinline__ float tanh_f(float x){ return __fdividef(2.f, 1.f + __expf(-2.f*x)) - 1.f; }

__device__ __forceinline__ unsigned short bf16_rne(float f){
    uint32_t u = __float_as_uint(f);
    return (unsigned short)((u + 0x7FFFu + ((u >> 16) & 1u)) >> 16);
}

// ---------------------------------------------------------------------------
// Prep: split W0 [64][4096] fp32 into bf16 hi/lo planes (RNE + residual).
// ---------------------------------------------------------------------------
__global__ __launch_bounds__(256) void w0split(const float* __restrict__ W0,
                                               unsigned short* __restrict__ wh,
                                               unsigned short* __restrict__ wl)
{
    const int i = (blockIdx.x * 256 + threadIdx.x) * 4;
    float4 v = *(const float4*)(W0 + i);
    float f[4] = {v.x, v.y, v.z, v.w};
    unsigned short hh[4], ll[4];
    #pragma unroll
    for (int j = 0; j < 4; ++j) {
        unsigned short h = bf16_rne(f[j]);
        float fh = __uint_as_float((uint32_t)h << 16);
        hh[j] = h;
        ll[j] = bf16_rne(f[j] - fh);
    }
    *(ushort4*)(wh + i) = make_ushort4(hh[0], hh[1], hh[2], hh[3]);
    *(ushort4*)(wl + i) = make_ushort4(ll[0], ll[1], ll[2], ll[3]);
}

// ---------------------------------------------------------------------------
// Kernel 1: h1pre partials = x @ W0^T, bf16x3-split MFMA, split-K. (unchanged)
// ---------------------------------------------------------------------------
__global__ __launch_bounds__(256, 2) void fc_gemm1(
    const float* __restrict__ x,
    const unsigned short* __restrict__ wh,
    const unsigned short* __restrict__ wl,
    float* __restrict__ part)
{
    __shared__ __align__(16) unsigned short xh[2][64][64];
    __shared__ __align__(16) unsigned short xl[2][64][64];
    __shared__ __align__(16) unsigned short wh_s[2][64][64];
    __shared__ __align__(16) unsigned short wl_s[2][64][64];

    const int t   = threadIdx.x;
    const int l   = t & 63;
    const int w   = t >> 6;
    const int rbb = (w >> 1) * 32;
    const int cbb = (w & 1) * 32;
    const int r0  = blockIdx.x * 64;
    const int kb0 = blockIdx.y * KSLICE;

    const int srow = t >> 3;
    const int sg   = t & 7;

    f32x4 acc[2][2];
    #pragma unroll
    for (int i = 0; i < 2; ++i)
        #pragma unroll
        for (int j = 0; j < 2; ++j)
            acc[i][j] = (f32x4){0.f, 0.f, 0.f, 0.f};

    float4 xr[2][2];
    uint4  w0h[2], w0l[2];

    auto LOAD = [&](int c) {
        const float* xb = x + (size_t)r0 * FEAT + kb0 + c * BK;
        xr[0][0] = *(const float4*)(xb + (size_t)srow * FEAT + sg * 8);
        xr[0][1] = *(const float4*)(xb + (size_t)srow * FEAT + sg * 8 + 4);
        xr[1][0] = *(const float4*)(xb + (size_t)(srow + 32) * FEAT + sg * 8);
        xr[1][1] = *(const float4*)(xb + (size_t)(srow + 32) * FEAT + sg * 8 + 4);
        const int wo = kb0 + c * BK + sg * 8;
        w0h[0] = *(const uint4*)(wh + (size_t)srow * FEAT + wo);
        w0h[1] = *(const uint4*)(wh + (size_t)(srow + 32) * FEAT + wo);
        w0l[0] = *(const uint4*)(wl + (size_t)srow * FEAT + wo);
        w0l[1] = *(const uint4*)(wl + (size_t)(srow + 32) * FEAT + wo);
    };

    auto STORE = [&](int c) {
        const int buf = c & 1;
        #pragma unroll
        for (int j = 0; j < 2; ++j) {
            const int row = srow + j * 32;
            const int gsw = (sg ^ (row & 7)) * 8;
            float f0[8] = {xr[j][0].x, xr[j][0].y, xr[j][0].z, xr[j][0].w,
                           xr[j][1].x, xr[j][1].y, xr[j][1].z, xr[j][1].w};
            u16x8 vh, vl;
            #pragma unroll
            for (int i = 0; i < 8; ++i) {
                uint32_t u  = __float_as_uint(f0[i]);
                uint32_t rh = (u + 0x7FFFu + ((u >> 16) & 1u)) >> 16;
                vh[i] = (unsigned short)rh;
                float fl = f0[i] - __uint_as_float(rh << 16);
                uint32_t u2 = __float_as_uint(fl);
                vl[i] = (unsigned short)((u2 + 0x7FFFu + ((u2 >> 16) & 1u)) >> 16);
            }
            *(u16x8*)&xh[buf][row][gsw] = vh;
            *(u16x8*)&xl[buf][row][gsw] = vl;
            *(uint4*)&wh_s[buf][row][gsw] = w0h[j];
            *(uint4*)&wl_s[buf][row][gsw] = w0l[j];
        }
    };

    auto COMPUTE = [&](int buf) {
        #pragma unroll
        for (int kstep = 0; kstep < 2; ++kstep) {
            const int gA = kstep * 4 + (l >> 4);
            bf16x8 Ah[2], Al[2], Bh[2], Bl[2];
            #pragma unroll
            for (int rf = 0; rf < 2; ++rf) {
                const int ra  = rbb + rf * 16 + (l & 15);
                const int off = (gA ^ (ra & 7)) * 8;
                Ah[rf] = __builtin_bit_cast(bf16x8, *(const u16x8*)&xh[buf][ra][off]);
                Al[rf] = __builtin_bit_cast(bf16x8, *(const u16x8*)&xl[buf][ra][off]);
            }
            #pragma unroll
            for (int cf = 0; cf < 2; ++cf) {
                const int cb  = cbb + cf * 16 + (l & 15);
                const int off = (gA ^ (cb & 7)) * 8;
                Bh[cf] = __builtin_bit_cast(bf16x8, *(const u16x8*)&wh_s[buf][cb][off]);
                Bl[cf] = __builtin_bit_cast(bf16x8, *(const u16x8*)&wl_s[buf][cb][off]);
            }
            #pragma unroll
            for (int rf = 0; rf < 2; ++rf)
                #pragma unroll
                for (int cf = 0; cf < 2; ++cf) {
                    acc[rf][cf] = __builtin_amdgcn_mfma_f32_16x16x32_bf16(Ah[rf], Bh[cf], acc[rf][cf], 0, 0, 0);
                    acc[rf][cf] = __builtin_amdgcn_mfma_f32_16x16x32_bf16(Al[rf], Bh[cf], acc[rf][cf], 0, 0, 0);
                    acc[rf][cf] = __builtin_amdgcn_mfma_f32_16x16x32_bf16(Ah[rf], Bl[cf], acc[rf][cf], 0, 0, 0);
                }
        }
    };

    LOAD(0);
    for (int c = 0; c < NCHUNK; ++c) {
        STORE(c);
        if (c + 1 < NCHUNK) LOAD(c + 1);
        asm volatile("s_waitcnt lgkmcnt(0)" ::: "memory");
        __builtin_amdgcn_s_barrier();
        COMPUTE(c & 1);
    }

    #pragma unroll
    for (int rf = 0; rf < 2; ++rf)
        #pragma unroll
        for (int cf = 0; cf < 2; ++cf)
            #pragma unroll
            for (int r = 0; r < 4; ++r) {
                const int row = r0 + rbb + rf * 16 + (l >> 4) * 4 + r;
                const int col = cbb + cf * 16 + (l & 15);
                part[((size_t)blockIdx.y * MROWS + row) * 64 + col] = acc[rf][cf][r];
            }
}

// ---------------------------------------------------------------------------
// Kernel 2: reduce partials -> relu(h1) -> h2 -> gx0 (unchanged)
// ---------------------------------------------------------------------------
__global__ __launch_bounds__(256) void fc_tail(
    const float* __restrict__ part, const float* __restrict__ b0,
    const float* __restrict__ W1, const float* __restrict__ b1,
    const float* __restrict__ Wih0,
    const float* __restrict__ bih, const float* __restrict__ bhh,
    float* __restrict__ gx0)
{
    __shared__ __align__(16) float h1s[64][68];
    __shared__ __align__(16) float h2s[64][68];

    const int tid = threadIdx.x;
    const int tc  = tid & 15;
    const int tr  = tid >> 4;
    const int r0  = blockIdx.x * 64;

    {
        const int row = tid >> 2;
        const int c0  = (tid & 3) * 16;
        float4 s[4];
        #pragma unroll
        for (int i = 0; i < 4; ++i)
            s[i] = *(const float4*)(part + ((size_t)(r0 + row)) * 64 + c0 + 4 * i);
        #pragma unroll
        for (int ks = 1; ks < KS; ++ks)
            #pragma unroll
            for (int i = 0; i < 4; ++i) {
                float4 v = *(const float4*)(part + ((size_t)ks * MROWS + r0 + row) * 64 + c0 + 4 * i);
                s[i].x += v.x; s[i].y += v.y; s[i].z += v.z; s[i].w += v.w;
            }
        #pragma unroll
        for (int i = 0; i < 4; ++i) {
            float4 bv = *(const float4*)(b0 + c0 + 4 * i);
            float4 o;
            o.x = fmaxf(s[i].x + bv.x, 0.f);
            o.y = fmaxf(s[i].y + bv.y, 0.f);
            o.z = fmaxf(s[i].z + bv.z, 0.f);
            o.w = fmaxf(s[i].w + bv.w, 0.f);
            *(float4*)&h1s[row][c0 + 4 * i] = o;
        }
    }
    __syncthreads();

    float acc2[4][4] = {};
    #pragma unroll
    for (int k4 = 0; k4 < 16; ++k4) {
        const int k = k4 * 4;
        float4 a[4], wv[4];
        #pragma unroll
        for (int i = 0; i < 4; ++i) a[i] = *(const float4*)&h1s[tr * 4 + i][k];
        #pragma unroll
        for (int j = 0; j < 4; ++j) wv[j] = *(const float4*)(W1 + (size_t)(tc * 4 + j) * DIN + k);
        #pragma unroll
        for (int i = 0; i < 4; ++i)
            #pragma unroll
            for (int j = 0; j < 4; ++j)
                acc2[i][j] += a[i].x * wv[j].x + a[i].y * wv[j].y + a[i].z * wv[j].z + a[i].w * wv[j].w;
    }
    __syncthreads();
    #pragma unroll
    for (int i = 0; i < 4; ++i)
        #pragma unroll
        for (int j = 0; j < 4; ++j)
            h2s[tr * 4 + i][tc * 4 + j] = acc2[i][j] + b1[tc * 4 + j];
    __syncthreads();

    #pragma unroll
    for (int p = 0; p < 2; ++p) {
        float acc3[4][4] = {};
        #pragma unroll
        for (int k4 = 0; k4 < 16; ++k4) {
            const int k = k4 * 4;
            float4 a[4], wv[4];
            #pragma unroll
            for (int i = 0; i < 4; ++i) a[i] = *(const float4*)&h2s[tr * 4 + i][k];
            #pragma unroll
            for (int j = 0; j < 4; ++j) wv[j] = *(const float4*)(Wih0 + (size_t)(p * 64 + tc * 4 + j) * DIN + k);
            #pragma unroll
            for (int i = 0; i < 4; ++i)
                #pragma unroll
                for (int j = 0; j < 4; ++j)
                    acc3[i][j] += a[i].x * wv[j].x + a[i].y * wv[j].y + a[i].z * wv[j].z + a[i].w * wv[j].w;
        }
        const int g0 = p * 64 + tc * 4;
        #pragma unroll
        for (int i = 0; i < 4; ++i) {
            float4 ov;
            ov.x = acc3[i][0] + bih[g0 + 0] + bhh[g0 + 0];
            ov.y = acc3[i][1] + bih[g0 + 1] + bhh[g0 + 1];
            ov.z = acc3[i][2] + bih[g0 + 2] + bhh[g0 + 2];
            ov.w = acc3[i][3] + bih[g0 + 3] + bhh[g0 + 3];
            *(float4*)(gx0 + (size_t)(r0 + tr * 4 + i) * G4 + g0) = ov;
        }
    }
}

// ---------------------------------------------------------------------------
// Kernel 3: wavefront-pipelined LSTM, TWO LAYERS PER WAVE (4 waves, 256 thr).
// Superstep s: wave w evals layer 2w at t=s-w, then layer 2w+1 at same t.
// Intra-pair handoff = same-wave LDS + lgkmcnt(0), no barrier.
// ONE __syncthreads per superstep (303 barriers vs 607). Inner math = r2.
// 1 wave/SIMD -> no issue contention, full unified register budget.
// ---------------------------------------------------------------------------
__global__ __launch_bounds__(256, 1) void lstm_all(
    const float* __restrict__ gx0,
    const float* __restrict__ Wih, const float* __restrict__ Whh,
    const float* __restrict__ bih, const float* __restrict__ bhh,
    const float* __restrict__ Wfc1, const float* __restrict__ bfc1,
    const float* __restrict__ Wfc2, const float* __restrict__ bfc2,
    float* __restrict__ out)
{
    const int b    = blockIdx.x;
    const int tid  = threadIdx.x;
    const int w    = tid >> 6;      // wave id: owns layers 2w, 2w+1
    const int lane = tid & 63;
    const int q0   = lane;
    const int q1   = lane + 64;
    const int lA   = 2 * w;
    const int lB   = 2 * w + 1;

    __shared__ __align__(16) float hbuf[NL][2][HS];  // [layer][t parity][h]
    __shared__ __align__(16) float h7[TT][HS];
    __shared__ __align__(16) float gbuf[NW][G4];
    __shared__ float red[NW];

    // ---- weights for both layers (r2-style scalar arrays) ----
    float whhA0[HS], whhA1[HS], wihA0[HS], wihA1[HS];
    float whhB0[HS], whhB1[HS], wihB0[HS], wihB1[HS];
    {
        const float* whhl = Whh + (size_t)lA * G4 * HS;
        const float* wihl = Wih + (size_t)(lA > 0 ? lA - 1 : 0) * G4 * HS;
        #pragma unroll
        for (int k4 = 0; k4 < 8; ++k4) {
            float4 v0 = *(const float4*)(whhl + q0 * HS + 4 * k4);
            float4 v1 = *(const float4*)(whhl + q1 * HS + 4 * k4);
            whhA0[4*k4+0]=v0.x; whhA0[4*k4+1]=v0.y; whhA0[4*k4+2]=v0.z; whhA0[4*k4+3]=v0.w;
            whhA1[4*k4+0]=v1.x; whhA1[4*k4+1]=v1.y; whhA1[4*k4+2]=v1.z; whhA1[4*k4+3]=v1.w;
            float4 u0 = *(const float4*)(wihl + q0 * HS + 4 * k4);
            float4 u1 = *(const float4*)(wihl + q1 * HS + 4 * k4);
            wihA0[4*k4+0]=u0.x; wihA0[4*k4+1]=u0.y; wihA0[4*k4+2]=u0.z; wihA0[4*k4+3]=u0.w;
            wihA1[4*k4+0]=u1.x; wihA1[4*k4+1]=u1.y; wihA1[4*k4+2]=u1.z; wihA1[4*k4+3]=u1.w;
        }
        const float* whhm = Whh + (size_t)lB * G4 * HS;
        const float* wihm = Wih + (size_t)(lB - 1) * G4 * HS;
        #pragma unroll
        for (int k4 = 0; k4 < 8; ++k4) {
            float4 v0 = *(const float4*)(whhm + q0 * HS + 4 * k4);
            float4 v1 = *(const float4*)(whhm + q1 * HS + 4 * k4);
            whhB0[4*k4+0]=v0.x; whhB0[4*k4+1]=v0.y; whhB0[4*k4+2]=v0.z; whhB0[4*k4+3]=v0.w;
            whhB1[4*k4+0]=v1.x; whhB1[4*k4+1]=v1.y; whhB1[4*k4+2]=v1.z; whhB1[4*k4+3]=v1.w;
            float4 u0 = *(const float4*)(wihm + q0 * HS + 4 * k4);
            float4 u1 = *(const float4*)(wihm + q1 * HS + 4 * k4);
            wihB0[4*k4+0]=u0.x; wihB0[4*k4+1]=u0.y; wihB0[4*k4+2]=u0.z; wihB0[4*k4+3]=u0.w;
            wihB1[4*k4+0]=u1.x; wihB1[4*k4+1]=u1.y; wihB1[4*k4+2]=u1.z; wihB1[4*k4+3]=u1.w;
        }
    }
    const float biasA0 = (lA > 0) ? (bih[lA*G4 + q0] + bhh[lA*G4 + q0]) : 0.f;
    const float biasA1 = (lA > 0) ? (bih[lA*G4 + q1] + bhh[lA*G4 + q1]) : 0.f;
    const float biasB0 = bih[lB*G4 + q0] + bhh[lB*G4 + q0];
    const float biasB1 = bih[lB*G4 + q1] + bhh[lB*G4 + q1];

    float cA = 0.f, cB = 0.f;   // lanes 0..31 hold the real state

    const float* gxb = gx0 + (size_t)b * TT * G4;
    float pf0 = 0.f, pf1 = 0.f;
    if (w == 0) { pf0 = gxb[q0]; pf1 = gxb[q1]; }

    for (int s = 0; s < NSUP; ++s) {
        const int t = s - w;            // wave-uniform
        if (0 <= t && t < TT) {
            // ================= eval A: layer 2w at time t =================
            float acc0, acc1;
            if (w == 0) {
                acc0 = pf0; acc1 = pf1;
                const int tn = t + 1;
                if (tn < TT) { pf0 = gxb[(size_t)tn * G4 + q0]; pf1 = gxb[(size_t)tn * G4 + q1]; }
            } else {
                acc0 = biasA0; acc1 = biasA1;
            }
            {
                float a0a = 0.f, a0b = 0.f, a1a = 0.f, a1b = 0.f;
                if (t > 0) {
                    const float4* hp = (const float4*)hbuf[lA][(t - 1) & 1];
                    #pragma unroll
                    for (int k4 = 0; k4 < 8; ++k4) {
                        float4 v = hp[k4];
                        a0a = fmaf(whhA0[4*k4+0], v.x, a0a); a0b = fmaf(whhA0[4*k4+1], v.y, a0b);
                        a0a = fmaf(whhA0[4*k4+2], v.z, a0a); a0b = fmaf(whhA0[4*k4+3], v.w, a0b);
                        a1a = fmaf(whhA1[4*k4+0], v.x, a1a); a1b = fmaf(whhA1[4*k4+1], v.y, a1b);
                        a1a = fmaf(whhA1[4*k4+2], v.z, a1a); a1b = fmaf(whhA1[4*k4+3], v.w, a1b);
                    }
                }
                if (w > 0) {
                    const float4* hq = (const float4*)hbuf[lA - 1][t & 1];
                    #pragma unroll
                    for (int k4 = 0; k4 < 8; ++k4) {
                        float4 v = hq[k4];
                        a0a = fmaf(wihA0[4*k4+0], v.x, a0a); a0b = fmaf(wihA0[4*k4+1], v.y, a0b);
                        a0a = fmaf(wihA0[4*k4+2], v.z, a0a); a0b = fmaf(wihA0[4*k4+3], v.w, a0b);
                        a1a = fmaf(wihA1[4*k4+0], v.x, a1a); a1b = fmaf(wihA1[4*k4+1], v.y, a1b);
                        a1a = fmaf(wihA1[4*k4+2], v.z, a1a); a1b = fmaf(wihA1[4*k4+3], v.w, a1b);
                    }
                }
                acc0 += a0a + a0b;
                acc1 += a1a + a1b;
            }
            gbuf[w][q0] = acc0;
            gbuf[w][q1] = acc1;
            asm volatile("s_waitcnt lgkmcnt(0)" ::: "memory");
            if (lane < HS) {
                const float ig = gbuf[w][lane];
                const float fg = gbuf[w][HS + lane];
                const float gg = gbuf[w][2*HS + lane];
                const float og = gbuf[w][3*HS + lane];
                cA = sigm(fg) * cA + sigm(ig) * tanh_f(gg);
                const float hv = sigm(og) * tanh_f(cA);
                hbuf[lA][t & 1][lane] = hv;
            }
            asm volatile("s_waitcnt lgkmcnt(0)" ::: "memory");   // h_A[t] visible to own wave

            // ================= eval B: layer 2w+1 at time t =================
            float b0a = biasB0, b1a = biasB1;
            {
                float a0a = 0.f, a0b = 0.f, a1a = 0.f, a1b = 0.f;
                if (t > 0) {
                    const float4* hp = (const float4*)hbuf[lB][(t - 1) & 1];
                    #pragma unroll
                    for (int k4 = 0; k4 < 8; ++k4) {
                        float4 v = hp[k4];
                        a0a = fmaf(whhB0[4*k4+0], v.x, a0a); a0b = fmaf(whhB0[4*k4+1], v.y, a0b);
                        a0a = fmaf(whhB0[4*k4+2], v.z, a0a); a0b = fmaf(whhB0[4*k4+3], v.w, a0b);
                        a1a = fmaf(whhB1[4*k4+0], v.x, a1a); a1b = fmaf(whhB1[4*k4+1], v.y, a1b);
                        a1a = fmaf(whhB1[4*k4+2], v.z, a1a); a1b = fmaf(whhB1[4*k4+3], v.w, a1b);
                    }
                }
                {
                    const float4* hq = (const float4*)hbuf[lB - 1][t & 1];   // just written
                    #pragma unroll
                    for (int k4 = 0; k4 < 8; ++k4) {
                        float4 v = hq[k4];
                        a0a = fmaf(wihB0[4*k4+0], v.x, a0a); a0b = fmaf(wihB0[4*k4+1], v.y, a0b);
                        a0a = fmaf(wihB0[4*k4+2], v.z, a0a); a0b = fmaf(wihB0[4*k4+3], v.w, a0b);
                        a1a = fmaf(wihB1[4*k4+0], v.x, a1a); a1b = fmaf(wihB1[4*k4+1], v.y, a1b);
                        a1a = fmaf(wihB1[4*k4+2], v.z, a1a); a1b = fmaf(wihB1[4*k4+3], v.w, a1b);
                    }
                }
                b0a += a0a + a0b;
                b1a += a1a + a1b;
            }
            gbuf[w][q0] = b0a;
            gbuf[w][q1] = b1a;
            asm volatile("s_waitcnt lgkmcnt(0)" ::: "memory");
            if (lane < HS) {
                const float ig = gbuf[w][lane];
                const float fg = gbuf[w][HS + lane];
                const float gg = gbuf[w][2*HS + lane];
                const float og = gbuf[w][3*HS + lane];
                cB = sigm(fg) * cB + sigm(ig) * tanh_f(gg);
                const float hv = sigm(og) * tanh_f(cB);
                hbuf[lB][t & 1][lane] = hv;
                if (lB == NL - 1) h7[t][lane] = hv;
            }
        }
        __syncthreads();
    }

    // ---- fused fc1 (over H) + fc2 (over T) ----
    float part = 0.f;
    for (int t = tid; t < TT; t += 256) {
        float st = 0.f;
        #pragma unroll
        for (int j = 0; j < HS; ++j) st = fmaf(h7[t][j], Wfc1[j], st);
        part += (st + bfc1[0]) * Wfc2[t];
    }
    #pragma unroll
    for (int off = 32; off >= 1; off >>= 1) part += __shfl_down(part, off, 64);
    if (lane == 0) red[w] = part;
    __syncthreads();
    if (tid == 0) {
        float tot = 0.f;
        #pragma unroll
        for (int v = 0; v < NW; ++v) tot += red[v];
        out[b] = tot + bfc2[0];
    }
}

// ---------------------------------------------------------------------------
extern "C" void kernel_launch(void* const* d_in, const int* in_sizes, int n_in,
                              void* d_out, int out_size, void* d_ws, size_t ws_size,
                              hipStream_t stream) {
    const float* x    = (const float*)d_in[0];
    const float* W0   = (const float*)d_in[1];
    const float* b0   = (const float*)d_in[2];
    const float* W1   = (const float*)d_in[3];
    const float* b1   = (const float*)d_in[4];
    const float* Wih0 = (const float*)d_in[5];
    const float* Wih  = (const float*)d_in[6];
    const float* Whh  = (const float*)d_in[7];
    const float* bih  = (const float*)d_in[8];
    const float* bhh  = (const float*)d_in[9];
    const float* Wfc1 = (const float*)d_in[10];
    const float* bfc1 = (const float*)d_in[11];
    const float* Wfc2 = (const float*)d_in[12];
    const float* bfc2 = (const float*)d_in[13];

    char* wsb = (char*)d_ws;
    float*          gx0 = (float*)wsb;                                   // 9,830,400 B
    unsigned short* wh  = (unsigned short*)(wsb + 9830400);              //   524,288 B
    unsigned short* wl  = (unsigned short*)(wsb + 9830400 + 524288);     //   524,288 B
    float*          prt = (float*)(wsb + 9830400 + 1048576);             // 19,660,800 B

    w0split <<<256, 256, 0, stream>>>(W0, wh, wl);
    fc_gemm1<<<dim3(MROWS / 64, KS), 256, 0, stream>>>(x, wh, wl, prt);
    fc_tail <<<MROWS / 64, 256, 0, stream>>>(prt, b0, W1, b1, Wih0, bih, bhh, gx0);
    lstm_all<<<BB, 256, 0, stream>>>(gx0, Wih, Whh, bih, bhh, Wfc1, bfc1, Wfc2, bfc2,
                                     (float*)d_out);
}

// Round 8
// 470.809 us; speedup vs baseline: 1.2893x; 1.2893x over previous
//
#include <hip/hip_runtime.h>
#include <cstdint>

#define FEAT 4096
#define DIN  64
#define HS   32
#define NL   8
#define TT   300
#define BB   64
#define G4   128           // 4*HS
#define MROWS (BB*TT)      // 19200
#define KS    4            // K-split for big GEMM
#define KSLICE (FEAT/KS)   // 1024
#define BK    64
#define NCHUNK (KSLICE/BK) // 16
#define PAR   16           // h ring-buffer depth (power of 2)

typedef __bf16 bf16x8 __attribute__((ext_vector_type(8)));
typedef float  f32x4  __attribute__((ext_vector_type(4)));
typedef unsigned short u16x8 __attribute__((ext_vector_type(8)));

__device__ __forceinline__ float sigm(float x){ return __fdividef(1.f, 1.f + __expf(-x)); }
__device__ __forceinline__ float tanh_f(float x){ return __fdividef(2.f, 1.f + __expf(-2.f*x)) - 1.f; }

__device__ __forceinline__ unsigned short bf16_rne(float f){
    uint32_t u = __float_as_uint(f);
    return (unsigned short)((u + 0x7FFFu + ((u >> 16) & 1u)) >> 16);
}

// ---------------------------------------------------------------------------
// Prep: split W0 [64][4096] fp32 into bf16 hi/lo planes (RNE + residual).
// ---------------------------------------------------------------------------
__global__ __launch_bounds__(256) void w0split(const float* __restrict__ W0,
                                               unsigned short* __restrict__ wh,
                                               unsigned short* __restrict__ wl)
{
    const int i = (blockIdx.x * 256 + threadIdx.x) * 4;
    float4 v = *(const float4*)(W0 + i);
    float f[4] = {v.x, v.y, v.z, v.w};
    unsigned short hh[4], ll[4];
    #pragma unroll
    for (int j = 0; j < 4; ++j) {
        unsigned short h = bf16_rne(f[j]);
        float fh = __uint_as_float((uint32_t)h << 16);
        hh[j] = h;
        ll[j] = bf16_rne(f[j] - fh);
    }
    *(ushort4*)(wh + i) = make_ushort4(hh[0], hh[1], hh[2], hh[3]);
    *(ushort4*)(wl + i) = make_ushort4(ll[0], ll[1], ll[2], ll[3]);
}

// ---------------------------------------------------------------------------
// Kernel 1: h1pre partials = x @ W0^T, bf16x3-split MFMA, split-K. (unchanged)
// ---------------------------------------------------------------------------
__global__ __launch_bounds__(256, 2) void fc_gemm1(
    const float* __restrict__ x,
    const unsigned short* __restrict__ wh,
    const unsigned short* __restrict__ wl,
    float* __restrict__ part)
{
    __shared__ __align__(16) unsigned short xh[2][64][64];
    __shared__ __align__(16) unsigned short xl[2][64][64];
    __shared__ __align__(16) unsigned short wh_s[2][64][64];
    __shared__ __align__(16) unsigned short wl_s[2][64][64];

    const int t   = threadIdx.x;
    const int l   = t & 63;
    const int w   = t >> 6;
    const int rbb = (w >> 1) * 32;
    const int cbb = (w & 1) * 32;
    const int r0  = blockIdx.x * 64;
    const int kb0 = blockIdx.y * KSLICE;

    const int srow = t >> 3;
    const int sg   = t & 7;

    f32x4 acc[2][2];
    #pragma unroll
    for (int i = 0; i < 2; ++i)
        #pragma unroll
        for (int j = 0; j < 2; ++j)
            acc[i][j] = (f32x4){0.f, 0.f, 0.f, 0.f};

    float4 xr[2][2];
    uint4  w0h[2], w0l[2];

    auto LOAD = [&](int c) {
        const float* xb = x + (size_t)r0 * FEAT + kb0 + c * BK;
        xr[0][0] = *(const float4*)(xb + (size_t)srow * FEAT + sg * 8);
        xr[0][1] = *(const float4*)(xb + (size_t)srow * FEAT + sg * 8 + 4);
        xr[1][0] = *(const float4*)(xb + (size_t)(srow + 32) * FEAT + sg * 8);
        xr[1][1] = *(const float4*)(xb + (size_t)(srow + 32) * FEAT + sg * 8 + 4);
        const int wo = kb0 + c * BK + sg * 8;
        w0h[0] = *(const uint4*)(wh + (size_t)srow * FEAT + wo);
        w0h[1] = *(const uint4*)(wh + (size_t)(srow + 32) * FEAT + wo);
        w0l[0] = *(const uint4*)(wl + (size_t)srow * FEAT + wo);
        w0l[1] = *(const uint4*)(wl + (size_t)(srow + 32) * FEAT + wo);
    };

    auto STORE = [&](int c) {
        const int buf = c & 1;
        #pragma unroll
        for (int j = 0; j < 2; ++j) {
            const int row = srow + j * 32;
            const int gsw = (sg ^ (row & 7)) * 8;
            float f0[8] = {xr[j][0].x, xr[j][0].y, xr[j][0].z, xr[j][0].w,
                           xr[j][1].x, xr[j][1].y, xr[j][1].z, xr[j][1].w};
            u16x8 vh, vl;
            #pragma unroll
            for (int i = 0; i < 8; ++i) {
                uint32_t u  = __float_as_uint(f0[i]);
                uint32_t rh = (u + 0x7FFFu + ((u >> 16) & 1u)) >> 16;
                vh[i] = (unsigned short)rh;
                float fl = f0[i] - __uint_as_float(rh << 16);
                uint32_t u2 = __float_as_uint(fl);
                vl[i] = (unsigned short)((u2 + 0x7FFFu + ((u2 >> 16) & 1u)) >> 16);
            }
            *(u16x8*)&xh[buf][row][gsw] = vh;
            *(u16x8*)&xl[buf][row][gsw] = vl;
            *(uint4*)&wh_s[buf][row][gsw] = w0h[j];
            *(uint4*)&wl_s[buf][row][gsw] = w0l[j];
        }
    };

    auto COMPUTE = [&](int buf) {
        #pragma unroll
        for (int kstep = 0; kstep < 2; ++kstep) {
            const int gA = kstep * 4 + (l >> 4);
            bf16x8 Ah[2], Al[2], Bh[2], Bl[2];
            #pragma unroll
            for (int rf = 0; rf < 2; ++rf) {
                const int ra  = rbb + rf * 16 + (l & 15);
                const int off = (gA ^ (ra & 7)) * 8;
                Ah[rf] = __builtin_bit_cast(bf16x8, *(const u16x8*)&xh[buf][ra][off]);
                Al[rf] = __builtin_bit_cast(bf16x8, *(const u16x8*)&xl[buf][ra][off]);
            }
            #pragma unroll
            for (int cf = 0; cf < 2; ++cf) {
                const int cb  = cbb + cf * 16 + (l & 15);
                const int off = (gA ^ (cb & 7)) * 8;
                Bh[cf] = __builtin_bit_cast(bf16x8, *(const u16x8*)&wh_s[buf][cb][off]);
                Bl[cf] = __builtin_bit_cast(bf16x8, *(const u16x8*)&wl_s[buf][cb][off]);
            }
            #pragma unroll
            for (int rf = 0; rf < 2; ++rf)
                #pragma unroll
                for (int cf = 0; cf < 2; ++cf) {
                    acc[rf][cf] = __builtin_amdgcn_mfma_f32_16x16x32_bf16(Ah[rf], Bh[cf], acc[rf][cf], 0, 0, 0);
                    acc[rf][cf] = __builtin_amdgcn_mfma_f32_16x16x32_bf16(Al[rf], Bh[cf], acc[rf][cf], 0, 0, 0);
                    acc[rf][cf] = __builtin_amdgcn_mfma_f32_16x16x32_bf16(Ah[rf], Bl[cf], acc[rf][cf], 0, 0, 0);
                }
        }
    };

    LOAD(0);
    for (int c = 0; c < NCHUNK; ++c) {
        STORE(c);
        if (c + 1 < NCHUNK) LOAD(c + 1);
        asm volatile("s_waitcnt lgkmcnt(0)" ::: "memory");
        __builtin_amdgcn_s_barrier();
        COMPUTE(c & 1);
    }

    #pragma unroll
    for (int rf = 0; rf < 2; ++rf)
        #pragma unroll
        for (int cf = 0; cf < 2; ++cf)
            #pragma unroll
            for (int r = 0; r < 4; ++r) {
                const int row = r0 + rbb + rf * 16 + (l >> 4) * 4 + r;
                const int col = cbb + cf * 16 + (l & 15);
                part[((size_t)blockIdx.y * MROWS + row) * 64 + col] = acc[rf][cf][r];
            }
}

// ---------------------------------------------------------------------------
// Kernel 2: reduce partials -> relu(h1) -> h2 -> gx0 (unchanged)
// ---------------------------------------------------------------------------
__global__ __launch_bounds__(256) void fc_tail(
    const float* __restrict__ part, const float* __restrict__ b0,
    const float* __restrict__ W1, const float* __restrict__ b1,
    const float* __restrict__ Wih0,
    const float* __restrict__ bih, const float* __restrict__ bhh,
    float* __restrict__ gx0)
{
    __shared__ __align__(16) float h1s[64][68];
    __shared__ __align__(16) float h2s[64][68];

    const int tid = threadIdx.x;
    const int tc  = tid & 15;
    const int tr  = tid >> 4;
    const int r0  = blockIdx.x * 64;

    {
        const int row = tid >> 2;
        const int c0  = (tid & 3) * 16;
        float4 s[4];
        #pragma unroll
        for (int i = 0; i < 4; ++i)
            s[i] = *(const float4*)(part + ((size_t)(r0 + row)) * 64 + c0 + 4 * i);
        #pragma unroll
        for (int ks = 1; ks < KS; ++ks)
            #pragma unroll
            for (int i = 0; i < 4; ++i) {
                float4 v = *(const float4*)(part + ((size_t)ks * MROWS + r0 + row) * 64 + c0 + 4 * i);
                s[i].x += v.x; s[i].y += v.y; s[i].z += v.z; s[i].w += v.w;
            }
        #pragma unroll
        for (int i = 0; i < 4; ++i) {
            float4 bv = *(const float4*)(b0 + c0 + 4 * i);
            float4 o;
            o.x = fmaxf(s[i].x + bv.x, 0.f);
            o.y = fmaxf(s[i].y + bv.y, 0.f);
            o.z = fmaxf(s[i].z + bv.z, 0.f);
            o.w = fmaxf(s[i].w + bv.w, 0.f);
            *(float4*)&h1s[row][c0 + 4 * i] = o;
        }
    }
    __syncthreads();

    float acc2[4][4] = {};
    #pragma unroll
    for (int k4 = 0; k4 < 16; ++k4) {
        const int k = k4 * 4;
        float4 a[4], wv[4];
        #pragma unroll
        for (int i = 0; i < 4; ++i) a[i] = *(const float4*)&h1s[tr * 4 + i][k];
        #pragma unroll
        for (int j = 0; j < 4; ++j) wv[j] = *(const float4*)(W1 + (size_t)(tc * 4 + j) * DIN + k);
        #pragma unroll
        for (int i = 0; i < 4; ++i)
            #pragma unroll
            for (int j = 0; j < 4; ++j)
                acc2[i][j] += a[i].x * wv[j].x + a[i].y * wv[j].y + a[i].z * wv[j].z + a[i].w * wv[j].w;
    }
    __syncthreads();
    #pragma unroll
    for (int i = 0; i < 4; ++i)
        #pragma unroll
        for (int j = 0; j < 4; ++j)
            h2s[tr * 4 + i][tc * 4 + j] = acc2[i][j] + b1[tc * 4 + j];
    __syncthreads();

    #pragma unroll
    for (int p = 0; p < 2; ++p) {
        float acc3[4][4] = {};
        #pragma unroll
        for (int k4 = 0; k4 < 16; ++k4) {
            const int k = k4 * 4;
            float4 a[4], wv[4];
            #pragma unroll
            for (int i = 0; i < 4; ++i) a[i] = *(const float4*)&h2s[tr * 4 + i][k];
            #pragma unroll
            for (int j = 0; j < 4; ++j) wv[j] = *(const float4*)(Wih0 + (size_t)(p * 64 + tc * 4 + j) * DIN + k);
            #pragma unroll
            for (int i = 0; i < 4; ++i)
                #pragma unroll
                for (int j = 0; j < 4; ++j)
                    acc3[i][j] += a[i].x * wv[j].x + a[i].y * wv[j].y + a[i].z * wv[j].z + a[i].w * wv[j].w;
        }
        const int g0 = p * 64 + tc * 4;
        #pragma unroll
        for (int i = 0; i < 4; ++i) {
            float4 ov;
            ov.x = acc3[i][0] + bih[g0 + 0] + bhh[g0 + 0];
            ov.y = acc3[i][1] + bih[g0 + 1] + bhh[g0 + 1];
            ov.z = acc3[i][2] + bih[g0 + 2] + bhh[g0 + 2];
            ov.w = acc3[i][3] + bih[g0 + 3] + bhh[g0 + 3];
            *(float4*)(gx0 + (size_t)(r0 + tr * 4 + i) * G4 + g0) = ov;
        }
    }
}

// ---------------------------------------------------------------------------
// Kernel 3: ASYNC producer-consumer LSTM. No per-step block barrier.
// Wave l = layer l, self-paced over t=0..TT-1. Sync via LDS progress flags:
//   consumer: spin until progress[l-1] >= t, then read hbuf[l-1][t&15]
//   producer: write hbuf[l][t&15], lgkmcnt(0), lane0 sets progress[l] = t
//   back-pressure: before overwriting slot, ensure progress[l+1] >= t-PAR
// Inner per-eval math = r2 exact (gbuf exchange, scalar fma arrays).
// ---------------------------------------------------------------------------
__global__ __launch_bounds__(512, 2) void lstm_all(
    const float* __restrict__ gx0,
    const float* __restrict__ Wih, const float* __restrict__ Whh,
    const float* __restrict__ bih, const float* __restrict__ bhh,
    const float* __restrict__ Wfc1, const float* __restrict__ bfc1,
    const float* __restrict__ Wfc2, const float* __restrict__ bfc2,
    float* __restrict__ out)
{
    const int b    = blockIdx.x;
    const int tid  = threadIdx.x;
    const int l    = tid >> 6;
    const int lane = tid & 63;
    const int q0   = lane;
    const int q1   = lane + 64;

    __shared__ __align__(16) float hbuf[NL][PAR][HS];  // [layer][t & 15][h]
    __shared__ __align__(16) float h7[TT][HS];
    __shared__ __align__(16) float gbuf[NL][G4];
    __shared__ float red[NL];
    __shared__ int progress[NL];
    #define VPROG ((volatile int*)progress)

    if (tid < NL) VPROG[tid] = -1;

    // ---- weights (r2-style scalar arrays) ----
    float whh0[HS], whh1[HS], wih0[HS], wih1[HS];
    {
        const float* whhl = Whh + (size_t)l * G4 * HS;
        const float* wihl = Wih + (size_t)(l > 0 ? l - 1 : 0) * G4 * HS;
        #pragma unroll
        for (int k4 = 0; k4 < 8; ++k4) {
            float4 v0 = *(const float4*)(whhl + q0 * HS + 4 * k4);
            float4 v1 = *(const float4*)(whhl + q1 * HS + 4 * k4);
            whh0[4*k4+0]=v0.x; whh0[4*k4+1]=v0.y; whh0[4*k4+2]=v0.z; whh0[4*k4+3]=v0.w;
            whh1[4*k4+0]=v1.x; whh1[4*k4+1]=v1.y; whh1[4*k4+2]=v1.z; whh1[4*k4+3]=v1.w;
            float4 u0 = *(const float4*)(wihl + q0 * HS + 4 * k4);
            float4 u1 = *(const float4*)(wihl + q1 * HS + 4 * k4);
            wih0[4*k4+0]=u0.x; wih0[4*k4+1]=u0.y; wih0[4*k4+2]=u0.z; wih0[4*k4+3]=u0.w;
            wih1[4*k4+0]=u1.x; wih1[4*k4+1]=u1.y; wih1[4*k4+2]=u1.z; wih1[4*k4+3]=u1.w;
        }
    }
    const float bias0 = (l > 0) ? (bih[l*G4 + q0] + bhh[l*G4 + q0]) : 0.f;
    const float bias1 = (l > 0) ? (bih[l*G4 + q1] + bhh[l*G4 + q1]) : 0.f;

    float c_state = 0.f;

    const float* gxb = gx0 + (size_t)b * TT * G4;
    // depth-2 global prefetch for wave 0
    float pA0 = 0.f, pA1 = 0.f, pB0 = 0.f, pB1 = 0.f;
    if (l == 0) {
        pA0 = gxb[q0];      pA1 = gxb[q1];
        pB0 = gxb[G4 + q0]; pB1 = gxb[G4 + q1];
    }

    __syncthreads();   // progress init + weight loads settled

    for (int t = 0; t < TT; ++t) {
        float acc0, acc1;
        if (l == 0) {
            acc0 = pA0; acc1 = pA1;
            pA0 = pB0;  pA1 = pB1;
            const int tn = t + 2;
            if (tn < TT) { pB0 = gxb[(size_t)tn * G4 + q0]; pB1 = gxb[(size_t)tn * G4 + q1]; }
        } else {
            acc0 = bias0; acc1 = bias1;
            while (VPROG[l - 1] < t) { }          // wait for upstream h
        }
        if (l < NL - 1 && t >= PAR) {
            while (VPROG[l + 1] < t - PAR) { }    // ring back-pressure
        }
        asm volatile("" ::: "memory");            // no hoisting LDS reads above polls

        float a0a = 0.f, a0b = 0.f, a1a = 0.f, a1b = 0.f;
        if (l > 0) {
            const float4* hq = (const float4*)hbuf[l - 1][t & (PAR - 1)];
            #pragma unroll
            for (int k4 = 0; k4 < 8; ++k4) {
                float4 v = hq[k4];
                a0a = fmaf(wih0[4*k4+0], v.x, a0a); a0b = fmaf(wih0[4*k4+1], v.y, a0b);
                a0a = fmaf(wih0[4*k4+2], v.z, a0a); a0b = fmaf(wih0[4*k4+3], v.w, a0b);
                a1a = fmaf(wih1[4*k4+0], v.x, a1a); a1b = fmaf(wih1[4*k4+1], v.y, a1b);
                a1a = fmaf(wih1[4*k4+2], v.z, a1a); a1b = fmaf(wih1[4*k4+3], v.w, a1b);
            }
        }
        if (t > 0) {
            const float4* hp = (const float4*)hbuf[l][(t - 1) & (PAR - 1)];
            #pragma unroll
            for (int k4 = 0; k4 < 8; ++k4) {
                float4 v = hp[k4];
                a0a = fmaf(whh0[4*k4+0], v.x, a0a); a0b = fmaf(whh0[4*k4+1], v.y, a0b);
                a0a = fmaf(whh0[4*k4+2], v.z, a0a); a0b = fmaf(whh0[4*k4+3], v.w, a0b);
                a1a = fmaf(whh1[4*k4+0], v.x, a1a); a1b = fmaf(whh1[4*k4+1], v.y, a1b);
                a1a = fmaf(whh1[4*k4+2], v.z, a1a); a1b = fmaf(whh1[4*k4+3], v.w, a1b);
            }
        }
        acc0 += a0a + a0b;
        acc1 += a1a + a1b;

        // gate exchange (same-wave LDS round trip, r2-proven)
        gbuf[l][q0] = acc0;
        gbuf[l][q1] = acc1;
        asm volatile("s_waitcnt lgkmcnt(0)" ::: "memory");
        if (lane < HS) {
            const float ig = gbuf[l][lane];
            const float fg = gbuf[l][HS + lane];
            const float gg = gbuf[l][2*HS + lane];
            const float og = gbuf[l][3*HS + lane];
            c_state = sigm(fg) * c_state + sigm(ig) * tanh_f(gg);
            const float hv = sigm(og) * tanh_f(c_state);
            hbuf[l][t & (PAR - 1)][lane] = hv;
            if (l == NL - 1) h7[t][lane] = hv;
        }
        // publish: h write must complete before flag write
        asm volatile("s_waitcnt lgkmcnt(0)" ::: "memory");
        if (lane == 0) VPROG[l] = t;
    }

    __syncthreads();   // all layers done; h7 complete

    // ---- fused fc1 (over H) + fc2 (over T) ----
    float part = 0.f;
    for (int t = tid; t < TT; t += 512) {
        float st = 0.f;
        #pragma unroll
        for (int j = 0; j < HS; ++j) st = fmaf(h7[t][j], Wfc1[j], st);
        part += (st + bfc1[0]) * Wfc2[t];
    }
    #pragma unroll
    for (int off = 32; off >= 1; off >>= 1) part += __shfl_down(part, off, 64);
    if (lane == 0) red[l] = part;
    __syncthreads();
    if (tid == 0) {
        float tot = 0.f;
        #pragma unroll
        for (int w = 0; w < NL; ++w) tot += red[w];
        out[b] = tot + bfc2[0];
    }
}

// ---------------------------------------------------------------------------
extern "C" void kernel_launch(void* const* d_in, const int* in_sizes, int n_in,
                              void* d_out, int out_size, void* d_ws, size_t ws_size,
                              hipStream_t stream) {
    const float* x    = (const float*)d_in[0];
    const float* W0   = (const float*)d_in[1];
    const float* b0   = (const float*)d_in[2];
    const float* W1   = (const float*)d_in[3];
    const float* b1   = (const float*)d_in[4];
    const float* Wih0 = (const float*)d_in[5];
    const float* Wih  = (const float*)d_in[6];
    const float* Whh  = (const float*)d_in[7];
    const float* bih  = (const float*)d_in[8];
    const float* bhh  = (const float*)d_in[9];
    const float* Wfc1 = (const float*)d_in[10];
    const float* bfc1 = (const float*)d_in[11];
    const float* Wfc2 = (const float*)d_in[12];
    const float* bfc2 = (const float*)d_in[13];

    char* wsb = (char*)d_ws;
    float*          gx0 = (float*)wsb;                                   // 9,830,400 B
    unsigned short* wh  = (unsigned short*)(wsb + 9830400);              //   524,288 B
    unsigned short* wl  = (unsigned short*)(wsb + 9830400 + 524288);     //   524,288 B
    float*          prt = (float*)(wsb + 9830400 + 1048576);             // 19,660,800 B

    w0split <<<256, 256, 0, stream>>>(W0, wh, wl);
    fc_gemm1<<<dim3(MROWS / 64, KS), 256, 0, stream>>>(x, wh, wl, prt);
    fc_tail <<<MROWS / 64, 256, 0, stream>>>(prt, b0, W1, b1, Wih0, bih, bhh, gx0);
    lstm_all<<<BB, 512, 0, stream>>>(gx0, Wih, Whh, bih, bhh, Wfc1, bfc1, Wfc2, bfc2,
                                     (float*)d_out);
}

// Round 9
// 443.894 us; speedup vs baseline: 1.3675x; 1.0606x over previous
//
#include <hip/hip_runtime.h>
#include <cstdint>

#define FEAT 4096
#define DIN  64
#define HS   32
#define NL   8
#define TT   300
#define BB   64
#define G4   128           // 4*HS
#define MROWS (BB*TT)      // 19200
#define KS    4            // K-split for big GEMM
#define KSLICE (FEAT/KS)   // 1024
#define BK    64
#define NCHUNK (KSLICE/BK) // 16

typedef __bf16 bf16x8 __attribute__((ext_vector_type(8)));
typedef float  f32x4  __attribute__((ext_vector_type(4)));
typedef unsigned short u16x8 __attribute__((ext_vector_type(8)));

__device__ __forceinline__ float sigm(float x){ return __fdividef(1.f, 1.f + __expf(-x)); }
__device__ __forceinline__ float tanh_f(float x){ return __fdividef(2.f, 1.f + __expf(-2.f*x)) - 1.f; }

__device__ __forceinline__ unsigned short bf16_rne(float f){
    uint32_t u = __float_as_uint(f);
    return (unsigned short)((u + 0x7FFFu + ((u >> 16) & 1u)) >> 16);
}

// non-rematerializable 4x float4 load -> arch VGPRs (weight pinning)
__device__ __forceinline__ void ld4_pin(const float* p0, const float* p1,
                                        const float* p2, const float* p3,
                                        float4& a, float4& b, float4& c, float4& d) {
    asm volatile(
        "global_load_dwordx4 %0, %4, off\n\t"
        "global_load_dwordx4 %1, %5, off\n\t"
        "global_load_dwordx4 %2, %6, off\n\t"
        "global_load_dwordx4 %3, %7, off\n\t"
        "s_waitcnt vmcnt(0)"
        : "=&v"(a), "=&v"(b), "=&v"(c), "=&v"(d)
        : "v"(p0), "v"(p1), "v"(p2), "v"(p3)
        : "memory");
}

// ---------------------------------------------------------------------------
// Prep: split W0 [64][4096] fp32 into bf16 hi/lo planes (RNE + residual).
// ---------------------------------------------------------------------------
__global__ __launch_bounds__(256) void w0split(const float* __restrict__ W0,
                                               unsigned short* __restrict__ wh,
                                               unsigned short* __restrict__ wl)
{
    const int i = (blockIdx.x * 256 + threadIdx.x) * 4;
    float4 v = *(const float4*)(W0 + i);
    float f[4] = {v.x, v.y, v.z, v.w};
    unsigned short hh[4], ll[4];
    #pragma unroll
    for (int j = 0; j < 4; ++j) {
        unsigned short h = bf16_rne(f[j]);
        float fh = __uint_as_float((uint32_t)h << 16);
        hh[j] = h;
        ll[j] = bf16_rne(f[j] - fh);
    }
    *(ushort4*)(wh + i) = make_ushort4(hh[0], hh[1], hh[2], hh[3]);
    *(ushort4*)(wl + i) = make_ushort4(ll[0], ll[1], ll[2], ll[3]);
}

// ---------------------------------------------------------------------------
// Kernel 1: h1pre partials = x @ W0^T, bf16x3-split MFMA, split-K. (unchanged)
// ---------------------------------------------------------------------------
__global__ __launch_bounds__(256, 2) void fc_gemm1(
    const float* __restrict__ x,
    const unsigned short* __restrict__ wh,
    const unsigned short* __restrict__ wl,
    float* __restrict__ part)
{
    __shared__ __align__(16) unsigned short xh[2][64][64];
    __shared__ __align__(16) unsigned short xl[2][64][64];
    __shared__ __align__(16) unsigned short wh_s[2][64][64];
    __shared__ __align__(16) unsigned short wl_s[2][64][64];

    const int t   = threadIdx.x;
    const int l   = t & 63;
    const int w   = t >> 6;
    const int rbb = (w >> 1) * 32;
    const int cbb = (w & 1) * 32;
    const int r0  = blockIdx.x * 64;
    const int kb0 = blockIdx.y * KSLICE;

    const int srow = t >> 3;
    const int sg   = t & 7;

    f32x4 acc[2][2];
    #pragma unroll
    for (int i = 0; i < 2; ++i)
        #pragma unroll
        for (int j = 0; j < 2; ++j)
            acc[i][j] = (f32x4){0.f, 0.f, 0.f, 0.f};

    float4 xr[2][2];
    uint4  w0h[2], w0l[2];

    auto LOAD = [&](int c) {
        const float* xb = x + (size_t)r0 * FEAT + kb0 + c * BK;
        xr[0][0] = *(const float4*)(xb + (size_t)srow * FEAT + sg * 8);
        xr[0][1] = *(const float4*)(xb + (size_t)srow * FEAT + sg * 8 + 4);
        xr[1][0] = *(const float4*)(xb + (size_t)(srow + 32) * FEAT + sg * 8);
        xr[1][1] = *(const float4*)(xb + (size_t)(srow + 32) * FEAT + sg * 8 + 4);
        const int wo = kb0 + c * BK + sg * 8;
        w0h[0] = *(const uint4*)(wh + (size_t)srow * FEAT + wo);
        w0h[1] = *(const uint4*)(wh + (size_t)(srow + 32) * FEAT + wo);
        w0l[0] = *(const uint4*)(wl + (size_t)srow * FEAT + wo);
        w0l[1] = *(const uint4*)(wl + (size_t)(srow + 32) * FEAT + wo);
    };

    auto STORE = [&](int c) {
        const int buf = c & 1;
        #pragma unroll
        for (int j = 0; j < 2; ++j) {
            const int row = srow + j * 32;
            const int gsw = (sg ^ (row & 7)) * 8;
            float f0[8] = {xr[j][0].x, xr[j][0].y, xr[j][0].z, xr[j][0].w,
                           xr[j][1].x, xr[j][1].y, xr[j][1].z, xr[j][1].w};
            u16x8 vh, vl;
            #pragma unroll
            for (int i = 0; i < 8; ++i) {
                uint32_t u  = __float_as_uint(f0[i]);
                uint32_t rh = (u + 0x7FFFu + ((u >> 16) & 1u)) >> 16;
                vh[i] = (unsigned short)rh;
                float fl = f0[i] - __uint_as_float(rh << 16);
                uint32_t u2 = __float_as_uint(fl);
                vl[i] = (unsigned short)((u2 + 0x7FFFu + ((u2 >> 16) & 1u)) >> 16);
            }
            *(u16x8*)&xh[buf][row][gsw] = vh;
            *(u16x8*)&xl[buf][row][gsw] = vl;
            *(uint4*)&wh_s[buf][row][gsw] = w0h[j];
            *(uint4*)&wl_s[buf][row][gsw] = w0l[j];
        }
    };

    auto COMPUTE = [&](int buf) {
        #pragma unroll
        for (int kstep = 0; kstep < 2; ++kstep) {
            const int gA = kstep * 4 + (l >> 4);
            bf16x8 Ah[2], Al[2], Bh[2], Bl[2];
            #pragma unroll
            for (int rf = 0; rf < 2; ++rf) {
                const int ra  = rbb + rf * 16 + (l & 15);
                const int off = (gA ^ (ra & 7)) * 8;
                Ah[rf] = __builtin_bit_cast(bf16x8, *(const u16x8*)&xh[buf][ra][off]);
                Al[rf] = __builtin_bit_cast(bf16x8, *(const u16x8*)&xl[buf][ra][off]);
            }
            #pragma unroll
            for (int cf = 0; cf < 2; ++cf) {
                const int cb  = cbb + cf * 16 + (l & 15);
                const int off = (gA ^ (cb & 7)) * 8;
                Bh[cf] = __builtin_bit_cast(bf16x8, *(const u16x8*)&wh_s[buf][cb][off]);
                Bl[cf] = __builtin_bit_cast(bf16x8, *(const u16x8*)&wl_s[buf][cb][off]);
            }
            #pragma unroll
            for (int rf = 0; rf < 2; ++rf)
                #pragma unroll
                for (int cf = 0; cf < 2; ++cf) {
                    acc[rf][cf] = __builtin_amdgcn_mfma_f32_16x16x32_bf16(Ah[rf], Bh[cf], acc[rf][cf], 0, 0, 0);
                    acc[rf][cf] = __builtin_amdgcn_mfma_f32_16x16x32_bf16(Al[rf], Bh[cf], acc[rf][cf], 0, 0, 0);
                    acc[rf][cf] = __builtin_amdgcn_mfma_f32_16x16x32_bf16(Ah[rf], Bl[cf], acc[rf][cf], 0, 0, 0);
                }
        }
    };

    LOAD(0);
    for (int c = 0; c < NCHUNK; ++c) {
        STORE(c);
        if (c + 1 < NCHUNK) LOAD(c + 1);
        asm volatile("s_waitcnt lgkmcnt(0)" ::: "memory");
        __builtin_amdgcn_s_barrier();
        COMPUTE(c & 1);
    }

    #pragma unroll
    for (int rf = 0; rf < 2; ++rf)
        #pragma unroll
        for (int cf = 0; cf < 2; ++cf)
            #pragma unroll
            for (int r = 0; r < 4; ++r) {
                const int row = r0 + rbb + rf * 16 + (l >> 4) * 4 + r;
                const int col = cbb + cf * 16 + (l & 15);
                part[((size_t)blockIdx.y * MROWS + row) * 64 + col] = acc[rf][cf][r];
            }
}

// ---------------------------------------------------------------------------
// Kernel 2: reduce partials -> relu(h1) -> h2 -> gxp.
// gxp layout: [b*T + t][unit m][gate 0..3] (i,f,g,o) for float4 reads in lstm.
// ---------------------------------------------------------------------------
__global__ __launch_bounds__(256) void fc_tail(
    const float* __restrict__ part, const float* __restrict__ b0,
    const float* __restrict__ W1, const float* __restrict__ b1,
    const float* __restrict__ Wih0,
    const float* __restrict__ bih, const float* __restrict__ bhh,
    float* __restrict__ gxp)
{
    __shared__ __align__(16) float h1s[64][68];
    __shared__ __align__(16) float h2s[64][68];

    const int tid = threadIdx.x;
    const int tc  = tid & 15;
    const int tr  = tid >> 4;
    const int r0  = blockIdx.x * 64;

    {
        const int row = tid >> 2;
        const int c0  = (tid & 3) * 16;
        float4 s[4];
        #pragma unroll
        for (int i = 0; i < 4; ++i)
            s[i] = *(const float4*)(part + ((size_t)(r0 + row)) * 64 + c0 + 4 * i);
        #pragma unroll
        for (int ks = 1; ks < KS; ++ks)
            #pragma unroll
            for (int i = 0; i < 4; ++i) {
                float4 v = *(const float4*)(part + ((size_t)ks * MROWS + r0 + row) * 64 + c0 + 4 * i);
                s[i].x += v.x; s[i].y += v.y; s[i].z += v.z; s[i].w += v.w;
            }
        #pragma unroll
        for (int i = 0; i < 4; ++i) {
            float4 bv = *(const float4*)(b0 + c0 + 4 * i);
            float4 o;
            o.x = fmaxf(s[i].x + bv.x, 0.f);
            o.y = fmaxf(s[i].y + bv.y, 0.f);
            o.z = fmaxf(s[i].z + bv.z, 0.f);
            o.w = fmaxf(s[i].w + bv.w, 0.f);
            *(float4*)&h1s[row][c0 + 4 * i] = o;
        }
    }
    __syncthreads();

    float acc2[4][4] = {};
    #pragma unroll
    for (int k4 = 0; k4 < 16; ++k4) {
        const int k = k4 * 4;
        float4 a[4], wv[4];
        #pragma unroll
        for (int i = 0; i < 4; ++i) a[i] = *(const float4*)&h1s[tr * 4 + i][k];
        #pragma unroll
        for (int j = 0; j < 4; ++j) wv[j] = *(const float4*)(W1 + (size_t)(tc * 4 + j) * DIN + k);
        #pragma unroll
        for (int i = 0; i < 4; ++i)
            #pragma unroll
            for (int j = 0; j < 4; ++j)
                acc2[i][j] += a[i].x * wv[j].x + a[i].y * wv[j].y + a[i].z * wv[j].z + a[i].w * wv[j].w;
    }
    __syncthreads();
    #pragma unroll
    for (int i = 0; i < 4; ++i)
        #pragma unroll
        for (int j = 0; j < 4; ++j)
            h2s[tr * 4 + i][tc * 4 + j] = acc2[i][j] + b1[tc * 4 + j];
    __syncthreads();

    #pragma unroll
    for (int p = 0; p < 2; ++p) {
        float acc3[4][4] = {};
        #pragma unroll
        for (int k4 = 0; k4 < 16; ++k4) {
            const int k = k4 * 4;
            float4 a[4], wv[4];
            #pragma unroll
            for (int i = 0; i < 4; ++i) a[i] = *(const float4*)&h2s[tr * 4 + i][k];
            #pragma unroll
            for (int j = 0; j < 4; ++j) wv[j] = *(const float4*)(Wih0 + (size_t)(p * 64 + tc * 4 + j) * DIN + k);
            #pragma unroll
            for (int i = 0; i < 4; ++i)
                #pragma unroll
                for (int j = 0; j < 4; ++j)
                    acc3[i][j] += a[i].x * wv[j].x + a[i].y * wv[j].y + a[i].z * wv[j].z + a[i].w * wv[j].w;
        }
        const int g0 = p * 64 + tc * 4;
        #pragma unroll
        for (int i = 0; i < 4; ++i) {
            #pragma unroll
            for (int jj = 0; jj < 4; ++jj) {
                const int cc  = tc * 4 + jj;               // 0..63
                const int m   = cc & 31;
                const int gi  = p * 2 + (cc >> 5);         // gate index 0..3
                const float v = acc3[i][jj] + bih[g0 + jj] + bhh[g0 + jj];
                gxp[(size_t)(r0 + tr * 4 + i) * G4 + m * 4 + gi] = v;
            }
        }
    }
}

// ---------------------------------------------------------------------------
// Kernel 3: wavefront-pipelined LSTM, 4-gates-per-lane layout.
// Lane l owns gate rows {m, m+32, m+64, m+96} (i,f,g,o of unit m=l&31) over
// k-half [(l>>5)*16, +16). One shfl_xor(32) per gate completes the reduction;
// every lane then holds all 4 gates of its unit -> NO gate LDS round trip.
// Weights pinned in VGPRs via inline-asm loads. Lockstep __syncthreads (r2).
// ---------------------------------------------------------------------------
__global__ __launch_bounds__(512, 1) void lstm_all(
    const float* __restrict__ gxp,
    const float* __restrict__ Wih, const float* __restrict__ Whh,
    const float* __restrict__ bih, const float* __restrict__ bhh,
    const float* __restrict__ Wfc1, const float* __restrict__ bfc1,
    const float* __restrict__ Wfc2, const float* __restrict__ bfc2,
    float* __restrict__ out)
{
    const int b    = blockIdx.x;
    const int tid  = threadIdx.x;
    const int l    = tid >> 6;
    const int lane = tid & 63;
    const int m    = lane & 31;          // hidden unit owned
    const int k0   = (lane >> 5) * 16;   // k-half owned

    __shared__ __align__(16) float hbuf[NL][2][HS];  // [layer][t parity][h]
    __shared__ __align__(16) float h7[TT][HS];
    __shared__ float red[NL];

    // ---- pinned weights: wh4[j][q] = Whh[l][j*32+m][k0+4q .. +4], same wi4 ----
    float4 wh4[4][4], wi4[4][4];
    {
        const float* wb = Whh + (size_t)l * G4 * HS;
        #pragma unroll
        for (int j = 0; j < 4; ++j) {
            const float* rp = wb + (size_t)(j * 32 + m) * HS + k0;
            ld4_pin(rp, rp + 4, rp + 8, rp + 12,
                    wh4[j][0], wh4[j][1], wh4[j][2], wh4[j][3]);
        }
    }
    if (l > 0) {
        const float* wb = Wih + (size_t)(l - 1) * G4 * HS;
        #pragma unroll
        for (int j = 0; j < 4; ++j) {
            const float* rp = wb + (size_t)(j * 32 + m) * HS + k0;
            ld4_pin(rp, rp + 4, rp + 8, rp + 12,
                    wi4[j][0], wi4[j][1], wi4[j][2], wi4[j][3]);
        }
    } else {
        #pragma unroll
        for (int j = 0; j < 4; ++j)
            #pragma unroll
            for (int q = 0; q < 4; ++q)
                wi4[j][q] = make_float4(0.f, 0.f, 0.f, 0.f);
    }

    float bias[4] = {0.f, 0.f, 0.f, 0.f};
    if (l > 0) {
        #pragma unroll
        for (int j = 0; j < 4; ++j)
            bias[j] = bih[l * G4 + j * 32 + m] + bhh[l * G4 + j * 32 + m];
    }

    float c_state = 0.f;   // lanes m and m+32 redundantly track unit m

    const float* gxb = gxp + (size_t)b * TT * G4;
    float4 pf = make_float4(0.f, 0.f, 0.f, 0.f);
    if (l == 0) pf = *(const float4*)(gxb + m * 4);

    for (int s = 0; s < TT + NL - 1; ++s) {
        const int t = s - l;            // wave-uniform
        if (0 <= t && t < TT) {
            float4 gin;
            if (l == 0) {
                gin = pf;
                const int tn = t + 1;
                if (tn < TT) pf = *(const float4*)(gxb + (size_t)tn * G4 + m * 4);
            }

            // ---- matvec partials over this lane's k-half ----
            float r0_ = 0.f, r1_ = 0.f, r2_ = 0.f, r3_ = 0.f;
            if (t > 0) {
                const float* hp = hbuf[l][(t - 1) & 1];
                float4 hv[4];
                #pragma unroll
                for (int q = 0; q < 4; ++q) hv[q] = *(const float4*)(hp + k0 + 4 * q);
                #pragma unroll
                for (int q = 0; q < 4; ++q) {
                    r0_ = fmaf(wh4[0][q].x, hv[q].x, r0_); r0_ = fmaf(wh4[0][q].y, hv[q].y, r0_);
                    r0_ = fmaf(wh4[0][q].z, hv[q].z, r0_); r0_ = fmaf(wh4[0][q].w, hv[q].w, r0_);
                    r1_ = fmaf(wh4[1][q].x, hv[q].x, r1_); r1_ = fmaf(wh4[1][q].y, hv[q].y, r1_);
                    r1_ = fmaf(wh4[1][q].z, hv[q].z, r1_); r1_ = fmaf(wh4[1][q].w, hv[q].w, r1_);
                    r2_ = fmaf(wh4[2][q].x, hv[q].x, r2_); r2_ = fmaf(wh4[2][q].y, hv[q].y, r2_);
                    r2_ = fmaf(wh4[2][q].z, hv[q].z, r2_); r2_ = fmaf(wh4[2][q].w, hv[q].w, r2_);
                    r3_ = fmaf(wh4[3][q].x, hv[q].x, r3_); r3_ = fmaf(wh4[3][q].y, hv[q].y, r3_);
                    r3_ = fmaf(wh4[3][q].z, hv[q].z, r3_); r3_ = fmaf(wh4[3][q].w, hv[q].w, r3_);
                }
            }
            if (l > 0) {
                const float* hq = hbuf[l - 1][t & 1];
                float4 hv[4];
                #pragma unroll
                for (int q = 0; q < 4; ++q) hv[q] = *(const float4*)(hq + k0 + 4 * q);
                #pragma unroll
                for (int q = 0; q < 4; ++q) {
                    r0_ = fmaf(wi4[0][q].x, hv[q].x, r0_); r0_ = fmaf(wi4[0][q].y, hv[q].y, r0_);
                    r0_ = fmaf(wi4[0][q].z, hv[q].z, r0_); r0_ = fmaf(wi4[0][q].w, hv[q].w, r0_);
                    r1_ = fmaf(wi4[1][q].x, hv[q].x, r1_); r1_ = fmaf(wi4[1][q].y, hv[q].y, r1_);
                    r1_ = fmaf(wi4[1][q].z, hv[q].z, r1_); r1_ = fmaf(wi4[1][q].w, hv[q].w, r1_);
                    r2_ = fmaf(wi4[2][q].x, hv[q].x, r2_); r2_ = fmaf(wi4[2][q].y, hv[q].y, r2_);
                    r2_ = fmaf(wi4[2][q].z, hv[q].z, r2_); r2_ = fmaf(wi4[2][q].w, hv[q].w, r2_);
                    r3_ = fmaf(wi4[3][q].x, hv[q].x, r3_); r3_ = fmaf(wi4[3][q].y, hv[q].y, r3_);
                    r3_ = fmaf(wi4[3][q].z, hv[q].z, r3_); r3_ = fmaf(wi4[3][q].w, hv[q].w, r3_);
                }
            }

            // ---- cross-half reduction: both halves get full gate sums ----
            float gi = r0_ + __shfl_xor(r0_, 32, 64);
            float gf = r1_ + __shfl_xor(r1_, 32, 64);
            float gg = r2_ + __shfl_xor(r2_, 32, 64);
            float go = r3_ + __shfl_xor(r3_, 32, 64);
            if (l == 0) { gi += gin.x; gf += gin.y; gg += gin.z; go += gin.w; }
            else        { gi += bias[0]; gf += bias[1]; gg += bias[2]; go += bias[3]; }

            c_state = sigm(gf) * c_state + sigm(gi) * tanh_f(gg);
            const float hv = sigm(go) * tanh_f(c_state);

            if (lane < HS) {
                hbuf[l][t & 1][lane] = hv;
                if (l == NL - 1) h7[t][lane] = hv;
            }
        }
        __syncthreads();
    }

    // ---- fused fc1 (over H) + fc2 (over T) ----
    float part = 0.f;
    for (int t = tid; t < TT; t += 512) {
        float st = 0.f;
        #pragma unroll
        for (int j = 0; j < HS; ++j) st = fmaf(h7[t][j], Wfc1[j], st);
        part += (st + bfc1[0]) * Wfc2[t];
    }
    #pragma unroll
    for (int off = 32; off >= 1; off >>= 1) part += __shfl_down(part, off, 64);
    if (lane == 0) red[l] = part;
    __syncthreads();
    if (tid == 0) {
        float tot = 0.f;
        #pragma unroll
        for (int w = 0; w < NL; ++w) tot += red[w];
        out[b] = tot + bfc2[0];
    }
}

// ---------------------------------------------------------------------------
extern "C" void kernel_launch(void* const* d_in, const int* in_sizes, int n_in,
                              void* d_out, int out_size, void* d_ws, size_t ws_size,
                              hipStream_t stream) {
    const float* x    = (const float*)d_in[0];
    const float* W0   = (const float*)d_in[1];
    const float* b0   = (const float*)d_in[2];
    const float* W1   = (const float*)d_in[3];
    const float* b1   = (const float*)d_in[4];
    const float* Wih0 = (const float*)d_in[5];
    const float* Wih  = (const float*)d_in[6];
    const float* Whh  = (const float*)d_in[7];
    const float* bih  = (const float*)d_in[8];
    const float* bhh  = (const float*)d_in[9];
    const float* Wfc1 = (const float*)d_in[10];
    const float* bfc1 = (const float*)d_in[11];
    const float* Wfc2 = (const float*)d_in[12];
    const float* bfc2 = (const float*)d_in[13];

    char* wsb = (char*)d_ws;
    float*          gxp = (float*)wsb;                                   // 9,830,400 B
    unsigned short* wh  = (unsigned short*)(wsb + 9830400);              //   524,288 B
    unsigned short* wl  = (unsigned short*)(wsb + 9830400 + 524288);     //   524,288 B
    float*          prt = (float*)(wsb + 9830400 + 1048576);             // 19,660,800 B

    w0split <<<256, 256, 0, stream>>>(W0, wh, wl);
    fc_gemm1<<<dim3(MROWS / 64, KS), 256, 0, stream>>>(x, wh, wl, prt);
    fc_tail <<<MROWS / 64, 256, 0, stream>>>(prt, b0, W1, b1, Wih0, bih, bhh, gxp);
    lstm_all<<<BB, 512, 0, stream>>>(gxp, Wih, Whh, bih, bhh, Wfc1, bfc1, Wfc2, bfc2,
                                     (float*)d_out);
}

// Round 10
// 437.961 us; speedup vs baseline: 1.3860x; 1.0135x over previous
//
#include <hip/hip_runtime.h>
#include <cstdint>

#define FEAT 4096
#define DIN  64
#define HS   32
#define NL   8
#define TT   300
#define BB   64
#define G4   128           // 4*HS
#define MROWS (BB*TT)      // 19200
#define KS    4            // K-split for big GEMM
#define KSLICE (FEAT/KS)   // 1024
#define BK    64
#define NCHUNK (KSLICE/BK) // 16

typedef __bf16 bf16x8 __attribute__((ext_vector_type(8)));
typedef float  f32x4  __attribute__((ext_vector_type(4)));
typedef unsigned short u16x8 __attribute__((ext_vector_type(8)));

__device__ __forceinline__ float sigm(float x){ return __fdividef(1.f, 1.f + __expf(-x)); }
__device__ __forceinline__ float tanh_f(float x){ return __fdividef(2.f, 1.f + __expf(-2.f*x)) - 1.f; }

__device__ __forceinline__ unsigned short bf16_rne(float f){
    uint32_t u = __float_as_uint(f);
    return (unsigned short)((u + 0x7FFFu + ((u >> 16) & 1u)) >> 16);
}

// ---------------------------------------------------------------------------
// Prep: split W0 [64][4096] fp32 into bf16 hi/lo planes (RNE + residual).
// ---------------------------------------------------------------------------
__global__ __launch_bounds__(256) void w0split(const float* __restrict__ W0,
                                               unsigned short* __restrict__ wh,
                                               unsigned short* __restrict__ wl)
{
    const int i = (blockIdx.x * 256 + threadIdx.x) * 4;
    float4 v = *(const float4*)(W0 + i);
    float f[4] = {v.x, v.y, v.z, v.w};
    unsigned short hh[4], ll[4];
    #pragma unroll
    for (int j = 0; j < 4; ++j) {
        unsigned short h = bf16_rne(f[j]);
        float fh = __uint_as_float((uint32_t)h << 16);
        hh[j] = h;
        ll[j] = bf16_rne(f[j] - fh);
    }
    *(ushort4*)(wh + i) = make_ushort4(hh[0], hh[1], hh[2], hh[3]);
    *(ushort4*)(wl + i) = make_ushort4(ll[0], ll[1], ll[2], ll[3]);
}

// ---------------------------------------------------------------------------
// Kernel 1: h1pre partials = x @ W0^T, bf16x3-split MFMA, split-K.
// Round-10 change: x hi/lo split via PLAIN CASTS so the compiler emits
// v_cvt_pk_bf16_f32 pairs (~3 VALU/float) instead of hand-rolled integer
// RNE (~10 VALU/float). Everything else identical to the r2 version.
// ---------------------------------------------------------------------------
__global__ __launch_bounds__(256, 2) void fc_gemm1(
    const float* __restrict__ x,
    const unsigned short* __restrict__ wh,
    const unsigned short* __restrict__ wl,
    float* __restrict__ part)
{
    __shared__ __align__(16) unsigned short xh[2][64][64];
    __shared__ __align__(16) unsigned short xl[2][64][64];
    __shared__ __align__(16) unsigned short wh_s[2][64][64];
    __shared__ __align__(16) unsigned short wl_s[2][64][64];

    const int t   = threadIdx.x;
    const int l   = t & 63;
    const int w   = t >> 6;
    const int rbb = (w >> 1) * 32;
    const int cbb = (w & 1) * 32;
    const int r0  = blockIdx.x * 64;
    const int kb0 = blockIdx.y * KSLICE;

    const int srow = t >> 3;
    const int sg   = t & 7;

    f32x4 acc[2][2];
    #pragma unroll
    for (int i = 0; i < 2; ++i)
        #pragma unroll
        for (int j = 0; j < 2; ++j)
            acc[i][j] = (f32x4){0.f, 0.f, 0.f, 0.f};

    float4 xr[2][2];
    uint4  w0h[2], w0l[2];

    auto LOAD = [&](int c) {
        const float* xb = x + (size_t)r0 * FEAT + kb0 + c * BK;
        xr[0][0] = *(const float4*)(xb + (size_t)srow * FEAT + sg * 8);
        xr[0][1] = *(const float4*)(xb + (size_t)srow * FEAT + sg * 8 + 4);
        xr[1][0] = *(const float4*)(xb + (size_t)(srow + 32) * FEAT + sg * 8);
        xr[1][1] = *(const float4*)(xb + (size_t)(srow + 32) * FEAT + sg * 8 + 4);
        const int wo = kb0 + c * BK + sg * 8;
        w0h[0] = *(const uint4*)(wh + (size_t)srow * FEAT + wo);
        w0h[1] = *(const uint4*)(wh + (size_t)(srow + 32) * FEAT + wo);
        w0l[0] = *(const uint4*)(wl + (size_t)srow * FEAT + wo);
        w0l[1] = *(const uint4*)(wl + (size_t)(srow + 32) * FEAT + wo);
    };

    auto STORE = [&](int c) {
        const int buf = c & 1;
        #pragma unroll
        for (int j = 0; j < 2; ++j) {
            const int row = srow + j * 32;
            const int gsw = (sg ^ (row & 7)) * 8;
            float f0[8] = {xr[j][0].x, xr[j][0].y, xr[j][0].z, xr[j][0].w,
                           xr[j][1].x, xr[j][1].y, xr[j][1].z, xr[j][1].w};
            u16x8 vh, vl;
            #pragma unroll
            for (int i = 0; i < 8; ++i) {
                const __bf16 bh = (__bf16)f0[i];              // RNE, pairs -> v_cvt_pk_bf16_f32
                const float  fh = (float)bh;
                const __bf16 bl = (__bf16)(f0[i] - fh);
                vh[i] = __builtin_bit_cast(unsigned short, bh);
                vl[i] = __builtin_bit_cast(unsigned short, bl);
            }
            *(u16x8*)&xh[buf][row][gsw] = vh;
            *(u16x8*)&xl[buf][row][gsw] = vl;
            *(uint4*)&wh_s[buf][row][gsw] = w0h[j];
            *(uint4*)&wl_s[buf][row][gsw] = w0l[j];
        }
    };

    auto COMPUTE = [&](int buf) {
        #pragma unroll
        for (int kstep = 0; kstep < 2; ++kstep) {
            const int gA = kstep * 4 + (l >> 4);
            bf16x8 Ah[2], Al[2], Bh[2], Bl[2];
            #pragma unroll
            for (int rf = 0; rf < 2; ++rf) {
                const int ra  = rbb + rf * 16 + (l & 15);
                const int off = (gA ^ (ra & 7)) * 8;
                Ah[rf] = __builtin_bit_cast(bf16x8, *(const u16x8*)&xh[buf][ra][off]);
                Al[rf] = __builtin_bit_cast(bf16x8, *(const u16x8*)&xl[buf][ra][off]);
            }
            #pragma unroll
            for (int cf = 0; cf < 2; ++cf) {
                const int cb  = cbb + cf * 16 + (l & 15);
                const int off = (gA ^ (cb & 7)) * 8;
                Bh[cf] = __builtin_bit_cast(bf16x8, *(const u16x8*)&wh_s[buf][cb][off]);
                Bl[cf] = __builtin_bit_cast(bf16x8, *(const u16x8*)&wl_s[buf][cb][off]);
            }
            #pragma unroll
            for (int rf = 0; rf < 2; ++rf)
                #pragma unroll
                for (int cf = 0; cf < 2; ++cf) {
                    acc[rf][cf] = __builtin_amdgcn_mfma_f32_16x16x32_bf16(Ah[rf], Bh[cf], acc[rf][cf], 0, 0, 0);
                    acc[rf][cf] = __builtin_amdgcn_mfma_f32_16x16x32_bf16(Al[rf], Bh[cf], acc[rf][cf], 0, 0, 0);
                    acc[rf][cf] = __builtin_amdgcn_mfma_f32_16x16x32_bf16(Ah[rf], Bl[cf], acc[rf][cf], 0, 0, 0);
                }
        }
    };

    LOAD(0);
    for (int c = 0; c < NCHUNK; ++c) {
        STORE(c);
        if (c + 1 < NCHUNK) LOAD(c + 1);
        asm volatile("s_waitcnt lgkmcnt(0)" ::: "memory");
        __builtin_amdgcn_s_barrier();
        COMPUTE(c & 1);
    }

    #pragma unroll
    for (int rf = 0; rf < 2; ++rf)
        #pragma unroll
        for (int cf = 0; cf < 2; ++cf)
            #pragma unroll
            for (int r = 0; r < 4; ++r) {
                const int row = r0 + rbb + rf * 16 + (l >> 4) * 4 + r;
                const int col = cbb + cf * 16 + (l & 15);
                part[((size_t)blockIdx.y * MROWS + row) * 64 + col] = acc[rf][cf][r];
            }
}

// ---------------------------------------------------------------------------
// Kernel 2: reduce partials -> relu(h1) -> h2 -> gx0 (r2 verbatim)
// ---------------------------------------------------------------------------
__global__ __launch_bounds__(256) void fc_tail(
    const float* __restrict__ part, const float* __restrict__ b0,
    const float* __restrict__ W1, const float* __restrict__ b1,
    const float* __restrict__ Wih0,
    const float* __restrict__ bih, const float* __restrict__ bhh,
    float* __restrict__ gx0)
{
    __shared__ __align__(16) float h1s[64][68];
    __shared__ __align__(16) float h2s[64][68];

    const int tid = threadIdx.x;
    const int tc  = tid & 15;
    const int tr  = tid >> 4;
    const int r0  = blockIdx.x * 64;

    {
        const int row = tid >> 2;
        const int c0  = (tid & 3) * 16;
        float4 s[4];
        #pragma unroll
        for (int i = 0; i < 4; ++i)
            s[i] = *(const float4*)(part + ((size_t)(r0 + row)) * 64 + c0 + 4 * i);
        #pragma unroll
        for (int ks = 1; ks < KS; ++ks)
            #pragma unroll
            for (int i = 0; i < 4; ++i) {
                float4 v = *(const float4*)(part + ((size_t)ks * MROWS + r0 + row) * 64 + c0 + 4 * i);
                s[i].x += v.x; s[i].y += v.y; s[i].z += v.z; s[i].w += v.w;
            }
        #pragma unroll
        for (int i = 0; i < 4; ++i) {
            float4 bv = *(const float4*)(b0 + c0 + 4 * i);
            float4 o;
            o.x = fmaxf(s[i].x + bv.x, 0.f);
            o.y = fmaxf(s[i].y + bv.y, 0.f);
            o.z = fmaxf(s[i].z + bv.z, 0.f);
            o.w = fmaxf(s[i].w + bv.w, 0.f);
            *(float4*)&h1s[row][c0 + 4 * i] = o;
        }
    }
    __syncthreads();

    float acc2[4][4] = {};
    #pragma unroll
    for (int k4 = 0; k4 < 16; ++k4) {
        const int k = k4 * 4;
        float4 a[4], wv[4];
        #pragma unroll
        for (int i = 0; i < 4; ++i) a[i] = *(const float4*)&h1s[tr * 4 + i][k];
        #pragma unroll
        for (int j = 0; j < 4; ++j) wv[j] = *(const float4*)(W1 + (size_t)(tc * 4 + j) * DIN + k);
        #pragma unroll
        for (int i = 0; i < 4; ++i)
            #pragma unroll
            for (int j = 0; j < 4; ++j)
                acc2[i][j] += a[i].x * wv[j].x + a[i].y * wv[j].y + a[i].z * wv[j].z + a[i].w * wv[j].w;
    }
    __syncthreads();
    #pragma unroll
    for (int i = 0; i < 4; ++i)
        #pragma unroll
        for (int j = 0; j < 4; ++j)
            h2s[tr * 4 + i][tc * 4 + j] = acc2[i][j] + b1[tc * 4 + j];
    __syncthreads();

    #pragma unroll
    for (int p = 0; p < 2; ++p) {
        float acc3[4][4] = {};
        #pragma unroll
        for (int k4 = 0; k4 < 16; ++k4) {
            const int k = k4 * 4;
            float4 a[4], wv[4];
            #pragma unroll
            for (int i = 0; i < 4; ++i) a[i] = *(const float4*)&h2s[tr * 4 + i][k];
            #pragma unroll
            for (int j = 0; j < 4; ++j) wv[j] = *(const float4*)(Wih0 + (size_t)(p * 64 + tc * 4 + j) * DIN + k);
            #pragma unroll
            for (int i = 0; i < 4; ++i)
                #pragma unroll
                for (int j = 0; j < 4; ++j)
                    acc3[i][j] += a[i].x * wv[j].x + a[i].y * wv[j].y + a[i].z * wv[j].z + a[i].w * wv[j].w;
        }
        const int g0 = p * 64 + tc * 4;
        #pragma unroll
        for (int i = 0; i < 4; ++i) {
            float4 ov;
            ov.x = acc3[i][0] + bih[g0 + 0] + bhh[g0 + 0];
            ov.y = acc3[i][1] + bih[g0 + 1] + bhh[g0 + 1];
            ov.z = acc3[i][2] + bih[g0 + 2] + bhh[g0 + 2];
            ov.w = acc3[i][3] + bih[g0 + 3] + bhh[g0 + 3];
            *(float4*)(gx0 + (size_t)(r0 + tr * 4 + i) * G4 + g0) = ov;
        }
    }
}

// ---------------------------------------------------------------------------
// Kernel 3: wavefront-pipelined LSTM — r2 verbatim (best measured variant:
// 270 µs; r3-r9 structural variants all landed 270-446 µs).
// ---------------------------------------------------------------------------
__global__ __launch_bounds__(512, 2) void lstm_all(
    const float* __restrict__ gx0,
    const float* __restrict__ Wih, const float* __restrict__ Whh,
    const float* __restrict__ bih, const float* __restrict__ bhh,
    const float* __restrict__ Wfc1, const float* __restrict__ bfc1,
    const float* __restrict__ Wfc2, const float* __restrict__ bfc2,
    float* __restrict__ out)
{
    const int b    = blockIdx.x;
    const int tid  = threadIdx.x;
    const int l    = tid >> 6;
    const int lane = tid & 63;
    const int q0   = lane;
    const int q1   = lane + 64;

    __shared__ __align__(16) float hbuf[NL][2][HS];
    __shared__ __align__(16) float gbuf[NL][G4];
    __shared__ __align__(16) float h7[TT][HS];
    __shared__ float red[NL];

    float whh0[HS], whh1[HS], wih0[HS], wih1[HS];
    {
        const float* whhl = Whh + (size_t)l * G4 * HS;
        const float* wihl = Wih + (size_t)(l > 0 ? l - 1 : 0) * G4 * HS;
        #pragma unroll
        for (int k4 = 0; k4 < 8; ++k4) {
            float4 v0 = *(const float4*)(whhl + q0 * HS + 4 * k4);
            float4 v1 = *(const float4*)(whhl + q1 * HS + 4 * k4);
            whh0[4*k4+0]=v0.x; whh0[4*k4+1]=v0.y; whh0[4*k4+2]=v0.z; whh0[4*k4+3]=v0.w;
            whh1[4*k4+0]=v1.x; whh1[4*k4+1]=v1.y; whh1[4*k4+2]=v1.z; whh1[4*k4+3]=v1.w;
            float4 u0 = *(const float4*)(wihl + q0 * HS + 4 * k4);
            float4 u1 = *(const float4*)(wihl + q1 * HS + 4 * k4);
            wih0[4*k4+0]=u0.x; wih0[4*k4+1]=u0.y; wih0[4*k4+2]=u0.z; wih0[4*k4+3]=u0.w;
            wih1[4*k4+0]=u1.x; wih1[4*k4+1]=u1.y; wih1[4*k4+2]=u1.z; wih1[4*k4+3]=u1.w;
        }
    }
    const float bias0 = (l > 0) ? (bih[l*G4 + q0] + bhh[l*G4 + q0]) : 0.f;
    const float bias1 = (l > 0) ? (bih[l*G4 + q1] + bhh[l*G4 + q1]) : 0.f;

    float c_state = 0.f;

    const float* gxb = gx0 + (size_t)b * TT * G4;
    float pf0 = 0.f, pf1 = 0.f;
    if (l == 0) { pf0 = gxb[q0]; pf1 = gxb[q1]; }

    for (int s = 0; s < TT + NL - 1; ++s) {
        const int t = s - l;
        if (0 <= t && t < TT) {
            float acc0, acc1;
            if (l == 0) {
                acc0 = pf0; acc1 = pf1;
                const int tn = t + 1;
                if (tn < TT) { pf0 = gxb[(size_t)tn * G4 + q0]; pf1 = gxb[(size_t)tn * G4 + q1]; }
            } else {
                acc0 = bias0; acc1 = bias1;
            }
            float a0a = 0.f, a0b = 0.f, a1a = 0.f, a1b = 0.f;
            if (t > 0) {
                const float4* hp = (const float4*)hbuf[l][(t - 1) & 1];
                #pragma unroll
                for (int k4 = 0; k4 < 8; ++k4) {
                    float4 v = hp[k4];
                    a0a = fmaf(whh0[4*k4+0], v.x, a0a); a0b = fmaf(whh0[4*k4+1], v.y, a0b);
                    a0a = fmaf(whh0[4*k4+2], v.z, a0a); a0b = fmaf(whh0[4*k4+3], v.w, a0b);
                    a1a = fmaf(whh1[4*k4+0], v.x, a1a); a1b = fmaf(whh1[4*k4+1], v.y, a1b);
                    a1a = fmaf(whh1[4*k4+2], v.z, a1a); a1b = fmaf(whh1[4*k4+3], v.w, a1b);
                }
            }
            if (l > 0) {
                const float4* hq = (const float4*)hbuf[l - 1][t & 1];
                #pragma unroll
                for (int k4 = 0; k4 < 8; ++k4) {
                    float4 v = hq[k4];
                    a0a = fmaf(wih0[4*k4+0], v.x, a0a); a0b = fmaf(wih0[4*k4+1], v.y, a0b);
                    a0a = fmaf(wih0[4*k4+2], v.z, a0a); a0b = fmaf(wih0[4*k4+3], v.w, a0b);
                    a1a = fmaf(wih1[4*k4+0], v.x, a1a); a1b = fmaf(wih1[4*k4+1], v.y, a1b);
                    a1a = fmaf(wih1[4*k4+2], v.z, a1a); a1b = fmaf(wih1[4*k4+3], v.w, a1b);
                }
            }
            acc0 += a0a + a0b;
            acc1 += a1a + a1b;
            gbuf[l][q0] = acc0;
            gbuf[l][q1] = acc1;
            asm volatile("s_waitcnt lgkmcnt(0)" ::: "memory");
            if (lane < HS) {
                const float ig = gbuf[l][lane];
                const float fg = gbuf[l][HS + lane];
                const float gg = gbuf[l][2*HS + lane];
                const float og = gbuf[l][3*HS + lane];
                c_state = sigm(fg) * c_state + sigm(ig) * tanh_f(gg);
                const float hv = sigm(og) * tanh_f(c_state);
                hbuf[l][t & 1][lane] = hv;
                if (l == NL - 1) h7[t][lane] = hv;
            }
        }
        __syncthreads();
    }

    float part = 0.f;
    for (int t = tid; t < TT; t += 512) {
        float st = 0.f;
        #pragma unroll
        for (int j = 0; j < HS; ++j) st = fmaf(h7[t][j], Wfc1[j], st);
        part += (st + bfc1[0]) * Wfc2[t];
    }
    #pragma unroll
    for (int off = 32; off >= 1; off >>= 1) part += __shfl_down(part, off, 64);
    if (lane == 0) red[l] = part;
    __syncthreads();
    if (tid == 0) {
        float tot = 0.f;
        #pragma unroll
        for (int w = 0; w < NL; ++w) tot += red[w];
        out[b] = tot + bfc2[0];
    }
}

// ---------------------------------------------------------------------------
extern "C" void kernel_launch(void* const* d_in, const int* in_sizes, int n_in,
                              void* d_out, int out_size, void* d_ws, size_t ws_size,
                              hipStream_t stream) {
    const float* x    = (const float*)d_in[0];
    const float* W0   = (const float*)d_in[1];
    const float* b0   = (const float*)d_in[2];
    const float* W1   = (const float*)d_in[3];
    const float* b1   = (const float*)d_in[4];
    const float* Wih0 = (const float*)d_in[5];
    const float* Wih  = (const float*)d_in[6];
    const float* Whh  = (const float*)d_in[7];
    const float* bih  = (const float*)d_in[8];
    const float* bhh  = (const float*)d_in[9];
    const float* Wfc1 = (const float*)d_in[10];
    const float* bfc1 = (const float*)d_in[11];
    const float* Wfc2 = (const float*)d_in[12];
    const float* bfc2 = (const float*)d_in[13];

    char* wsb = (char*)d_ws;
    float*          gx0 = (float*)wsb;                                   // 9,830,400 B
    unsigned short* wh  = (unsigned short*)(wsb + 9830400);              //   524,288 B
    unsigned short* wl  = (unsigned short*)(wsb + 9830400 + 524288);     //   524,288 B
    float*          prt = (float*)(wsb + 9830400 + 1048576);             // 19,660,800 B

    w0split <<<256, 256, 0, stream>>>(W0, wh, wl);
    fc_gemm1<<<dim3(MROWS / 64, KS), 256, 0, stream>>>(x, wh, wl, prt);
    fc_tail <<<MROWS / 64, 256, 0, stream>>>(prt, b0, W1, b1, Wih0, bih, bhh, gx0);
    lstm_all<<<BB, 512, 0, stream>>>(gx0, Wih, Whh, bih, bhh, Wfc1, bfc1, Wfc2, bfc2,
                                     (float*)d_out);
}